// Round 1
// baseline (190.970 us; speedup 1.0000x reference)
//
#include <hip/hip_runtime.h>

#define GRIDN 256
#define NVOX (GRIDN * GRIDN * GRIDN)   // 16,777,216 voxels, 64 MiB fp32

// ---------------------------------------------------------------------------
// Scatter: vol[d][h][w] += feats[i] for each active voxel.
// coords layout: coords[i] = (d, h, w), row-major [N,3] int32.
// ---------------------------------------------------------------------------
__global__ void k_scatter(const float* __restrict__ feats,
                          const int* __restrict__ coords,
                          float* __restrict__ vol, int n) {
    int i = blockIdx.x * blockDim.x + threadIdx.x;
    if (i >= n) return;
    int d = coords[3 * i + 0];
    int h = coords[3 * i + 1];
    int w = coords[3 * i + 2];
    atomicAdd(&vol[(d * GRIDN + h) * GRIDN + w], feats[i]);
}

// ---------------------------------------------------------------------------
// One separable 5-tap box pass along the axis with stride 2^LOG2S.
// out[i] = sum_{k=-2..2, 0 <= c+k < 256} in[i + k*2^LOG2S]
// where c = (i >> LOG2S) & 255 is the coordinate along that axis.
// ---------------------------------------------------------------------------
template <int LOG2S>
__global__ void k_boxpass(const float* __restrict__ in,
                          float* __restrict__ out, int total) {
    constexpr int S = 1 << LOG2S;
    int stride = gridDim.x * blockDim.x;
    for (int i = blockIdx.x * blockDim.x + threadIdx.x; i < total; i += stride) {
        int c = (i >> LOG2S) & (GRIDN - 1);
        float s = in[i];
        if (c >= 1)   s += in[i - S];
        if (c >= 2)   s += in[i - 2 * S];
        if (c <= GRIDN - 2) s += in[i + S];
        if (c <= GRIDN - 3) s += in[i + 2 * S];
        out[i] = s;
    }
}

// ---------------------------------------------------------------------------
// Fallback if ws is too small: expand each point into its clipped 5x5x5 box
// with atomics directly on the output (125 atomicAdds / point).
// ---------------------------------------------------------------------------
__global__ void k_scatter125(const float* __restrict__ feats,
                             const int* __restrict__ coords,
                             float* __restrict__ out, int n) {
    int i = blockIdx.x * blockDim.x + threadIdx.x;
    if (i >= n) return;
    int d = coords[3 * i + 0];
    int h = coords[3 * i + 1];
    int w = coords[3 * i + 2];
    float f = feats[i];
    int d0 = max(d - 2, 0), d1 = min(d + 2, GRIDN - 1);
    int h0 = max(h - 2, 0), h1 = min(h + 2, GRIDN - 1);
    int w0 = max(w - 2, 0), w1 = min(w + 2, GRIDN - 1);
    for (int dd = d0; dd <= d1; ++dd)
        for (int hh = h0; hh <= h1; ++hh)
            for (int ww = w0; ww <= w1; ++ww)
                atomicAdd(&out[(dd * GRIDN + hh) * GRIDN + ww], f);
}

extern "C" void kernel_launch(void* const* d_in, const int* in_sizes, int n_in,
                              void* d_out, int out_size, void* d_ws, size_t ws_size,
                              hipStream_t stream) {
    const float* feats  = (const float*)d_in[0];
    const int*   coords = (const int*)d_in[1];
    float*       out    = (float*)d_out;
    int n = in_sizes[0];

    const size_t vol_bytes = (size_t)NVOX * sizeof(float);

    if (ws_size >= vol_bytes) {
        float* vol = (float*)d_ws;
        // 1. Zero the dense volume, scatter active voxels.
        hipMemsetAsync(vol, 0, vol_bytes, stream);
        k_scatter<<<(n + 255) / 256, 256, 0, stream>>>(feats, coords, vol, n);
        // 2. Separable box sum: z (stride 65536), y (stride 256), x (stride 1).
        //    Ping-pong ws -> out -> ws -> out.
        const int blocks = 4096, threads = 256;
        k_boxpass<16><<<blocks, threads, 0, stream>>>(vol, out, NVOX);
        k_boxpass<8> <<<blocks, threads, 0, stream>>>(out, vol, NVOX);
        k_boxpass<0> <<<blocks, threads, 0, stream>>>(vol, out, NVOX);
    } else {
        // Fallback: direct 125-way atomic expansion.
        hipMemsetAsync(out, 0, vol_bytes, stream);
        k_scatter125<<<(n + 255) / 256, 256, 0, stream>>>(feats, coords, out, n);
    }
}

// Round 2
// 104.370 us; speedup vs baseline: 1.8297x; 1.8297x over previous
//
#include <hip/hip_runtime.h>

#define GRIDN 256
#define NVOX (GRIDN * GRIDN * GRIDN)   // 16,777,216 voxels, 64 MiB fp32

// ---------------------------------------------------------------------------
// Scatter: vol[d][h][w] += feats[i].
// ---------------------------------------------------------------------------
__global__ void k_scatter(const float* __restrict__ feats,
                          const int* __restrict__ coords,
                          float* __restrict__ vol, int n) {
    int i = blockIdx.x * blockDim.x + threadIdx.x;
    if (i >= n) return;
    int d = coords[3 * i + 0];
    int h = coords[3 * i + 1];
    int w = coords[3 * i + 2];
    atomicAdd(&vol[(d * GRIDN + h) * GRIDN + w], feats[i]);
}

// ---------------------------------------------------------------------------
// z-pass, float4-vectorized. Element stride along z = 65536 = 16384 float4.
// XCD-bijective block swizzle: each XCD streams a contiguous 1/8 chunk so the
// +-256/512 KB taps stay inside its 4 MB L2.
// ---------------------------------------------------------------------------
__global__ __launch_bounds__(256) void k_zpass(const float4* __restrict__ in,
                                               float4* __restrict__ out) {
    const int nb  = gridDim.x;          // 16384, divisible by 8
    const int cpx = nb >> 3;            // blocks per XCD chunk
    int b  = blockIdx.x;
    int sb = (b & 7) * cpx + (b >> 3);  // bijective (nb % 8 == 0)
    int i  = sb * 256 + threadIdx.x;    // float4 index, 0 .. NVOX/4
    int d  = (i >> 14) & (GRIDN - 1);   // z coordinate

    float4 s = in[i];
    if (d >= 1) { float4 a = in[i - 16384]; s.x += a.x; s.y += a.y; s.z += a.z; s.w += a.w; }
    if (d >= 2) { float4 a = in[i - 32768]; s.x += a.x; s.y += a.y; s.z += a.z; s.w += a.w; }
    if (d <= GRIDN - 2) { float4 a = in[i + 16384]; s.x += a.x; s.y += a.y; s.z += a.z; s.w += a.w; }
    if (d <= GRIDN - 3) { float4 a = in[i + 32768]; s.x += a.x; s.y += a.y; s.z += a.z; s.w += a.w; }
    out[i] = s;
}

// ---------------------------------------------------------------------------
// Fused y+x pass over one z-slice tile. Tile = 128(x) x 32(y) outputs.
// LDS: raw tile R[36][132] (halo 2 each side, zero-padded), x-passed Xp[36][128].
// ---------------------------------------------------------------------------
#define TX 128
#define TY 32
__global__ __launch_bounds__(256) void k_xypass(const float* __restrict__ in,
                                                float* __restrict__ out) {
    __shared__ float R[36][132];
    __shared__ float Xp[36][128];
    const int x0  = blockIdx.x * TX;
    const int y0  = blockIdx.y * TY;
    const int z   = blockIdx.z;
    const int tid = threadIdx.x;
    const float* slice = in + (size_t)z * (GRIDN * GRIDN);

    // Load 36x132 raw tile (zero-padded at volume edges). Rows are contiguous.
    for (int idx = tid; idx < 36 * 132; idx += 256) {
        int yy = idx / 132;
        int xx = idx - yy * 132;
        int gy = y0 + yy - 2;
        int gx = x0 + xx - 2;
        float v = 0.f;
        if ((unsigned)gy < GRIDN && (unsigned)gx < GRIDN)
            v = slice[gy * GRIDN + gx];
        R[yy][xx] = v;
    }
    __syncthreads();

    // x-pass: Xp[yy][x] = sum_{dx=0..4} R[yy][x+dx]
    for (int idx = tid; idx < 36 * 128; idx += 256) {
        int yy = idx >> 7;
        int x  = idx & 127;
        Xp[yy][x] = R[yy][x] + R[yy][x + 1] + R[yy][x + 2] + R[yy][x + 3] + R[yy][x + 4];
    }
    __syncthreads();

    // y-pass + store. Thread owns column x, 16 consecutive y rows.
    int x     = tid & 127;
    int yb    = tid >> 7;          // 0 or 1
    int ybase = yb * 16;
    float w0 = Xp[ybase + 0][x];
    float w1 = Xp[ybase + 1][x];
    float w2 = Xp[ybase + 2][x];
    float w3 = Xp[ybase + 3][x];
    float w4 = Xp[ybase + 4][x];
    float* op = out + (size_t)z * GRIDN * GRIDN + (size_t)(y0 + ybase) * GRIDN + (x0 + x);
    #pragma unroll
    for (int r = 0; r < 16; ++r) {
        *op = w0 + w1 + w2 + w3 + w4;
        op += GRIDN;
        w0 = w1; w1 = w2; w2 = w3; w3 = w4;
        if (r < 15) w4 = Xp[ybase + r + 5][x];
    }
}

// ---------------------------------------------------------------------------
// Fallback if ws is too small: direct 125-way atomic expansion.
// ---------------------------------------------------------------------------
__global__ void k_scatter125(const float* __restrict__ feats,
                             const int* __restrict__ coords,
                             float* __restrict__ out, int n) {
    int i = blockIdx.x * blockDim.x + threadIdx.x;
    if (i >= n) return;
    int d = coords[3 * i + 0];
    int h = coords[3 * i + 1];
    int w = coords[3 * i + 2];
    float f = feats[i];
    int d0 = max(d - 2, 0), d1 = min(d + 2, GRIDN - 1);
    int h0 = max(h - 2, 0), h1 = min(h + 2, GRIDN - 1);
    int w0 = max(w - 2, 0), w1 = min(w + 2, GRIDN - 1);
    for (int dd = d0; dd <= d1; ++dd)
        for (int hh = h0; hh <= h1; ++hh)
            for (int ww = w0; ww <= w1; ++ww)
                atomicAdd(&out[(dd * GRIDN + hh) * GRIDN + ww], f);
}

extern "C" void kernel_launch(void* const* d_in, const int* in_sizes, int n_in,
                              void* d_out, int out_size, void* d_ws, size_t ws_size,
                              hipStream_t stream) {
    const float* feats  = (const float*)d_in[0];
    const int*   coords = (const int*)d_in[1];
    float*       out    = (float*)d_out;
    int n = in_sizes[0];

    const size_t vol_bytes = (size_t)NVOX * sizeof(float);

    if (ws_size >= vol_bytes) {
        float* ws = (float*)d_ws;
        // 1. Zero d_out, scatter active voxels into it.
        hipMemsetAsync(out, 0, vol_bytes, stream);
        k_scatter<<<(n + 255) / 256, 256, 0, stream>>>(feats, coords, out, n);
        // 2. z-pass: out -> ws (float4, XCD-swizzled).
        k_zpass<<<NVOX / 4 / 256, 256, 0, stream>>>((const float4*)out, (float4*)ws);
        // 3. fused y+x pass: ws -> out.
        dim3 grid(GRIDN / TX, GRIDN / TY, GRIDN);
        k_xypass<<<grid, 256, 0, stream>>>(ws, out);
    } else {
        hipMemsetAsync(out, 0, vol_bytes, stream);
        k_scatter125<<<(n + 255) / 256, 256, 0, stream>>>(feats, coords, out, n);
    }
}